// Round 3
// baseline (8871.850 us; speedup 1.0000x reference)
//
#include <hip/hip_runtime.h>

// residual_LSTM: B=32, T=1024, H=C=512, L=2, fp32 in/out.
// R7: barrier restructure on top of R6 (128 WGs x 8ch, 2 N-tiles/wave).
//  (a) RMW-free barrier: per-WG epoch slot stores (64 slots/layer, one 64B-line
//      region); wave0 polls ALL slots with a 64-lane gather + __all. No atomic RMW
//      chain -> arrival is parallel, release = one LLC round trip.
//  (b) Per-layer decoupled barriers with skew: L0 gates on A>=s (own layer) and a lag
//      guard B>=s-2 (anti-clobber); L1 gates on A>=s && B>=s. h0pk is 4-deep (par=t&3)
//      so L0 may run up to 2 steps ahead; jitter of the two 64-WG pools stops adding.
//  (c) x register prefetch: x(t+1) loaded into 16xfloat4 VGPRs after the epilogue
//      sync; vmcnt drain lands inside the barrier-poll window -> next step's x-MFMA
//      starts with zero load wait.
// Carried: packed hi|lo bf16 h exchange over LLC (sc0 sc1, no fences), resid prefetch,
// fast exp/rcp transcendentals, LDS-resident swizzled weights, split-precision MFMA.

typedef unsigned int uint32;
typedef unsigned short ushort;

constexpr int B = 32, T = 1024, H = 512, NL = 2;
constexpr int KTOT = 2 * H;            // 1024 (combined [x;h] k-dim)
constexpr int BH   = B * H;            // 16384
constexpr size_t BTH = (size_t)B * T * H;
constexpr size_t BLH = (size_t)B * NL * H;

using bf16x8  = __attribute__((ext_vector_type(8))) short;
using floatx4 = __attribute__((ext_vector_type(4))) float;
using uint4v  = __attribute__((ext_vector_type(4))) uint32;

__device__ __forceinline__ float frcp(float x) { return __builtin_amdgcn_rcpf(x); }
__device__ __forceinline__ float sigm(float v) { return frcp(1.0f + __expf(-v)); }
__device__ __forceinline__ float tanh_fast(float v) {
    return 1.0f - 2.0f * frcp(1.0f + __expf(2.0f * v));
}

__device__ __forceinline__ ushort f2bf(float f) {        // RNE fp32 -> bf16 bits
    uint32 u = __builtin_bit_cast(uint32, f);
    u += 0x7fffu + ((u >> 16) & 1u);
    return (ushort)(u >> 16);
}

__launch_bounds__(512, 1)
__global__ void lstm_persist(const float* __restrict__ x,
                             const float* __restrict__ Wi,
                             const float* __restrict__ bi,
                             const float* __restrict__ Ws,
                             const float* __restrict__ bs,
                             float* __restrict__ out,
                             uint32* __restrict__ ctrl,
                             uint32* __restrict__ h0pk,   // [4][B][H] packed hi|lo<<16
                             uint32* __restrict__ h1pk)   // [2][B][H]
{
    extern __shared__ short smem[];
    short* whi = smem;                       // [32 rows][1024 k] bf16, swizzled 16B chunks
    short* wlo = smem + 32 * KTOT;
    float* red = (float*)(smem + 64 * KTOT); // [8 waves][2 nt][64 lanes][4] fp32 (16KB)

    const int wg    = blockIdx.x;            // 0..127
    const int tid   = threadIdx.x;           // 0..511
    const int layer = wg & 1;
    const int rg    = wg >> 1;               // row-group 0..63 (slot index within layer)
    const int chb   = rg * 8;                // 8 channels per WG

    // ---- stage + hi/lo split weights into LDS (once). local row n = gate*8 + c ----
    for (int i = tid; i < 32 * KTOT; i += 512) {
        const int n = i >> 10, k = i & (KTOT - 1);
        const int g = n >> 3, c = n & 7;
        const int grow = g * H + chb + c;
        const float v = (k < H) ? Wi[((size_t)layer * 4 * H + grow) * H + k]
                                : Ws[((size_t)layer * 4 * H + grow) * H + (k - H)];
        const ushort hb = f2bf(v);
        const float  hf = __builtin_bit_cast(float, (uint32)hb << 16);
        const ushort lb = f2bf(v - hf);
        const int off = (n * 128 + ((k >> 3) ^ n)) * 8 + (k & 7);   // XOR chunk swizzle
        whi[off] = (short)hb;
        wlo[off] = (short)lb;
    }

    const int lane = tid & 63;
    const int w    = tid >> 6;               // wave 0..7
    const int mt   = w & 1;                  // M-tile (batches mt*16..mt*16+15)
    const int kq   = w >> 1;                 // k-quarter (256 k each)
    const int quad = lane >> 4;
    const int mrow = lane & 15;
    const int bb   = mt * 16 + mrow;         // this lane's batch in A-frag
    const int nn   = mrow;                   // this lane's row within a B-tile

    const int ec = tid & 7, eb = tid >> 3;   // epilogue mapping (tid < 256)
    float cs = 0.f;
    float bias_[4] = {0.f, 0.f, 0.f, 0.f};
    if (tid < 256) {
        #pragma unroll
        for (int g = 0; g < 4; ++g) {
            const int grow = g * H + chb + ec;
            bias_[g] = bi[layer * 4 * H + grow] + bs[layer * 4 * H + grow];
        }
    }

    // ---- x prefetch registers (L0 x-path waves only): x(t) resident in VGPRs ----
    const bool xwave = (layer == 0) && (kq < 2);
    float4 xq[16];
    if (xwave) {
        const float* xb = x + ((size_t)bb * T + 0) * H + kq * 256 + quad * 8;
        #pragma unroll
        for (int st = 0; st < 8; ++st) {
            xq[2 * st]     = *(const float4*)(xb + st * 32);
            xq[2 * st + 1] = *(const float4*)(xb + st * 32 + 4);
        }
    }
    __syncthreads();

    for (int s = 0; s <= T; ++s) {
        const int t = (layer == 0) ? s : s - 1;
        const bool active = (t >= 0 && t < T);

        // ---- residual prefetch: issued before MFMA work, consumed in epilogue ----
        float resid = 0.f;
        if (active && tid < 256) {
            const int ch = chb + ec;
            if (layer == 0) {
                resid = x[((size_t)eb * T + t) * H + ch];
            } else {
                const uint32 rp = __hip_atomic_load(
                    &h0pk[(size_t)(t & 3) * BH + (size_t)eb * H + ch],
                    __ATOMIC_RELAXED, __HIP_MEMORY_SCOPE_AGENT);
                resid = __builtin_bit_cast(float, rp << 16)
                      + __builtin_bit_cast(float, rp & 0xffff0000u);
            }
        }

        if (active) {
            floatx4 acc0 = {0.f, 0.f, 0.f, 0.f};   // nt0 hi
            floatx4 acc1 = {0.f, 0.f, 0.f, 0.f};   // nt0 lo-corrections
            floatx4 acc2 = {0.f, 0.f, 0.f, 0.f};   // nt1 hi
            floatx4 acc3 = {0.f, 0.f, 0.f, 0.f};   // nt1 lo-corrections

            if (xwave) {
                // x path: data already in VGPRs (prefetched last step), split on the fly
                #pragma unroll
                for (int st = 0; st < 8; ++st) {
                    const float4 f0 = xq[2 * st], f1 = xq[2 * st + 1];
                    const float vv[8] = {f0.x, f0.y, f0.z, f0.w, f1.x, f1.y, f1.z, f1.w};
                    bf16x8 ahi, alo;
                    #pragma unroll
                    for (int j = 0; j < 8; ++j) {
                        const ushort hb = f2bf(vv[j]);
                        const float  hf = __builtin_bit_cast(float, (uint32)hb << 16);
                        ahi[j] = (short)hb;
                        alo[j] = (short)f2bf(vv[j] - hf);
                    }
                    const int cb = kq * 32 + st * 4 + quad;
                    const int n1 = 16 + nn;
                    const int woff0 = (nn * 128 + (cb ^ nn)) * 8;
                    const int woff1 = (n1 * 128 + (cb ^ n1)) * 8;
                    const bf16x8 bh0 = *(const bf16x8*)(whi + woff0);
                    const bf16x8 bl0 = *(const bf16x8*)(wlo + woff0);
                    const bf16x8 bh1 = *(const bf16x8*)(whi + woff1);
                    const bf16x8 bl1 = *(const bf16x8*)(wlo + woff1);
                    acc0 = __builtin_amdgcn_mfma_f32_16x16x32_bf16(ahi, bh0, acc0, 0, 0, 0);
                    acc1 = __builtin_amdgcn_mfma_f32_16x16x32_bf16(alo, bh0, acc1, 0, 0, 0);
                    acc1 = __builtin_amdgcn_mfma_f32_16x16x32_bf16(ahi, bl0, acc1, 0, 0, 0);
                    acc2 = __builtin_amdgcn_mfma_f32_16x16x32_bf16(ahi, bh1, acc2, 0, 0, 0);
                    acc3 = __builtin_amdgcn_mfma_f32_16x16x32_bf16(alo, bh1, acc3, 0, 0, 0);
                    acc3 = __builtin_amdgcn_mfma_f32_16x16x32_bf16(ahi, bl1, acc3, 0, 0, 0);
                }
            } else {
                // h path: packed coherent loads direct from LLC (sc0 sc1), one vmcnt wait
                int par, koff;
                const uint32* hbuf;
                if (layer == 0)   { par = (t - 1) & 3; koff = kq * 256 - 512; hbuf = h0pk; }
                else if (kq < 2)  { par = t & 3;       koff = kq * 256;       hbuf = h0pk; }
                else              { par = (t - 1) & 1; koff = kq * 256 - 512; hbuf = h1pk; }
                const uint32* hp = hbuf + (size_t)par * BH + (size_t)bb * H + koff + quad * 8;

                uint4v q0,q1,q2,q3,q4,q5,q6,q7,q8,q9,q10,q11,q12,q13,q14,q15;
                asm volatile(
                    "global_load_dwordx4 %0,  %16, off sc0 sc1\n\t"
                    "global_load_dwordx4 %1,  %16, off offset:16 sc0 sc1\n\t"
                    "global_load_dwordx4 %2,  %16, off offset:128 sc0 sc1\n\t"
                    "global_load_dwordx4 %3,  %16, off offset:144 sc0 sc1\n\t"
                    "global_load_dwordx4 %4,  %16, off offset:256 sc0 sc1\n\t"
                    "global_load_dwordx4 %5,  %16, off offset:272 sc0 sc1\n\t"
                    "global_load_dwordx4 %6,  %16, off offset:384 sc0 sc1\n\t"
                    "global_load_dwordx4 %7,  %16, off offset:400 sc0 sc1\n\t"
                    "global_load_dwordx4 %8,  %16, off offset:512 sc0 sc1\n\t"
                    "global_load_dwordx4 %9,  %16, off offset:528 sc0 sc1\n\t"
                    "global_load_dwordx4 %10, %16, off offset:640 sc0 sc1\n\t"
                    "global_load_dwordx4 %11, %16, off offset:656 sc0 sc1\n\t"
                    "global_load_dwordx4 %12, %16, off offset:768 sc0 sc1\n\t"
                    "global_load_dwordx4 %13, %16, off offset:784 sc0 sc1\n\t"
                    "global_load_dwordx4 %14, %16, off offset:896 sc0 sc1\n\t"
                    "global_load_dwordx4 %15, %16, off offset:912 sc0 sc1\n\t"
                    "s_waitcnt vmcnt(0)"
                    : "=&v"(q0), "=&v"(q1), "=&v"(q2), "=&v"(q3),
                      "=&v"(q4), "=&v"(q5), "=&v"(q6), "=&v"(q7),
                      "=&v"(q8), "=&v"(q9), "=&v"(q10), "=&v"(q11),
                      "=&v"(q12), "=&v"(q13), "=&v"(q14), "=&v"(q15)
                    : "v"(hp)
                    : "memory");
                const uint4v qq[16] = {q0,q1,q2,q3,q4,q5,q6,q7,q8,q9,q10,q11,q12,q13,q14,q15};

                #pragma unroll
                for (int st = 0; st < 8; ++st) {
                    const uint4v ea = qq[2 * st], eb4 = qq[2 * st + 1];   // elems 0-3, 4-7
                    uint4v hiw, low;
                    hiw[0] = __builtin_amdgcn_perm(ea[1],  ea[0],  0x05040100u);
                    hiw[1] = __builtin_amdgcn_perm(ea[3],  ea[2],  0x05040100u);
                    hiw[2] = __builtin_amdgcn_perm(eb4[1], eb4[0], 0x05040100u);
                    hiw[3] = __builtin_amdgcn_perm(eb4[3], eb4[2], 0x05040100u);
                    low[0] = __builtin_amdgcn_perm(ea[1],  ea[0],  0x07060302u);
                    low[1] = __builtin_amdgcn_perm(ea[3],  ea[2],  0x07060302u);
                    low[2] = __builtin_amdgcn_perm(eb4[1], eb4[0], 0x07060302u);
                    low[3] = __builtin_amdgcn_perm(eb4[3], eb4[2], 0x07060302u);
                    const bf16x8 ahi = __builtin_bit_cast(bf16x8, hiw);
                    const bf16x8 alo = __builtin_bit_cast(bf16x8, low);
                    const int cb = kq * 32 + st * 4 + quad;
                    const int n1 = 16 + nn;
                    const int woff0 = (nn * 128 + (cb ^ nn)) * 8;
                    const int woff1 = (n1 * 128 + (cb ^ n1)) * 8;
                    const bf16x8 bh0 = *(const bf16x8*)(whi + woff0);
                    const bf16x8 bl0 = *(const bf16x8*)(wlo + woff0);
                    const bf16x8 bh1 = *(const bf16x8*)(whi + woff1);
                    const bf16x8 bl1 = *(const bf16x8*)(wlo + woff1);
                    acc0 = __builtin_amdgcn_mfma_f32_16x16x32_bf16(ahi, bh0, acc0, 0, 0, 0);
                    acc1 = __builtin_amdgcn_mfma_f32_16x16x32_bf16(alo, bh0, acc1, 0, 0, 0);
                    acc1 = __builtin_amdgcn_mfma_f32_16x16x32_bf16(ahi, bl0, acc1, 0, 0, 0);
                    acc2 = __builtin_amdgcn_mfma_f32_16x16x32_bf16(ahi, bh1, acc2, 0, 0, 0);
                    acc3 = __builtin_amdgcn_mfma_f32_16x16x32_bf16(alo, bh1, acc3, 0, 0, 0);
                    acc3 = __builtin_amdgcn_mfma_f32_16x16x32_bf16(ahi, bl1, acc3, 0, 0, 0);
                }
            }
            floatx4 zr0, zr1;
            zr0[0] = acc0[0] + acc1[0]; zr0[1] = acc0[1] + acc1[1];
            zr0[2] = acc0[2] + acc1[2]; zr0[3] = acc0[3] + acc1[3];
            zr1[0] = acc2[0] + acc3[0]; zr1[1] = acc2[1] + acc3[1];
            zr1[2] = acc2[2] + acc3[2]; zr1[3] = acc2[3] + acc3[3];
            *(floatx4*)&red[((w * 2 + 0) * 64 + lane) * 4] = zr0;
            *(floatx4*)&red[((w * 2 + 1) * 64 + lane) * 4] = zr1;
        }
        __syncthreads();   // red visible to epilogue

        if (active && tid < 256) {
            // D layout (m89): col = lane&15, row(m) = (lane>>4)*4 + reg
            const int m = eb & 15, emt = eb >> 4, q = m >> 2, r = m & 3;
            const int ch = chb + ec;
            float z[4];
            #pragma unroll
            for (int g = 0; g < 4; ++g) {
                const int n = g * 8 + ec;          // local row 0..31
                const int nt = n >> 4, col = n & 15;
                const int li = q * 16 + col;
                float a = bias_[g];
                #pragma unroll
                for (int kqe = 0; kqe < 4; ++kqe)
                    a += red[((((kqe * 2 + emt) * 2) + nt) * 64 + li) * 4 + r];
                z[g] = a;
            }
            const float ig = sigm(z[0]), fg = sigm(z[1]);
            const float gg = tanh_fast(z[2]), og = sigm(z[3]);
            cs = ig * gg + fg * cs;
            const float hn = og * tanh_fast(cs) + resid;

            const ushort hb = f2bf(hn);
            const float  hf = __builtin_bit_cast(float, (uint32)hb << 16);
            const ushort lb = f2bf(hn - hf);
            const uint32 pk = (uint32)hb | ((uint32)lb << 16);
            if (layer == 0) {
                const size_t hidx = (size_t)(t & 3) * BH + (size_t)eb * H + ch;
                __hip_atomic_store(&h0pk[hidx], pk, __ATOMIC_RELAXED, __HIP_MEMORY_SCOPE_AGENT);
            } else {
                const size_t hidx = (size_t)(t & 1) * BH + (size_t)eb * H + ch;
                __hip_atomic_store(&h1pk[hidx], pk, __ATOMIC_RELAXED, __HIP_MEMORY_SCOPE_AGENT);
                out[((size_t)eb * T + t) * H + ch] = hn;
            }
            if (t == T - 1) {
                out[BTH + ((size_t)eb * NL + layer) * H + ch] = hn;
                out[BTH + BLH + ((size_t)eb * NL + layer) * H + ch] = cs;
            }
        }

        // ---- per-layer decoupled barrier, RMW-free.
        // Slots: ctrl[0..63] = layer0 epochs, ctrl[64..127] = layer1 epochs.
        // Arrival: one relaxed agent store to own slot. Release: wave0 gathers all 64
        // slots of each array (lane i <-> slot i) and __all's the condition.
        // L0 waits A>=e && B>=e-2 (skew guard, h0pk is 4-deep); L1 waits A>=e && B>=e.
        // __syncthreads (sync2 above) drained vmcnt -> h stores LLC-visible pre-arrival.
        __syncthreads();
        if (s < T) {
            // x prefetch for next step: issued here so the vmcnt drain of the final
            // __syncthreads lands inside the barrier-poll window.
            if (xwave && (s + 1) < T) {
                const float* xb = x + ((size_t)bb * T + (s + 1)) * H + kq * 256 + quad * 8;
                #pragma unroll
                for (int st = 0; st < 8; ++st) {
                    xq[2 * st]     = *(const float4*)(xb + st * 32);
                    xq[2 * st + 1] = *(const float4*)(xb + st * 32 + 4);
                }
            }
            const uint32 e = (uint32)s + 1u;
            if (tid == 0)
                __hip_atomic_store(&ctrl[layer * 64 + rg], e,
                                   __ATOMIC_RELAXED, __HIP_MEMORY_SCOPE_AGENT);
            if (tid < 64) {
                const uint32* pa = ctrl + tid;        // layer0 slots
                const uint32* pb = ctrl + 64 + tid;   // layer1 slots
                for (;;) {
                    uint32 a, b;
                    asm volatile("global_load_dword %0, %2, off sc0 sc1\n\t"
                                 "global_load_dword %1, %3, off sc0 sc1\n\t"
                                 "s_waitcnt vmcnt(0)"
                                 : "=&v"(a), "=&v"(b)
                                 : "v"(pa), "v"(pb)
                                 : "memory");
                    const bool ok = (layer == 0)
                        ? ((a >= e) && ((int)b >= (int)e - 2))
                        : ((a >= e) && (b >= e));
                    if (__all(ok)) break;
                    __builtin_amdgcn_s_sleep(1);
                }
            }
            __syncthreads();
        }
    }
}

extern "C" void kernel_launch(void* const* d_in, const int* in_sizes, int n_in,
                              void* d_out, int out_size, void* d_ws, size_t ws_size,
                              hipStream_t stream) {
    const float* x  = (const float*)d_in[0];
    const float* Wi = (const float*)d_in[1];
    const float* bi = (const float*)d_in[2];
    const float* Ws = (const float*)d_in[3];
    const float* bs = (const float*)d_in[4];
    float* out = (float*)d_out;

    // ws: ctrl 4KB | h0pk u32 [4][B][H] 256KB | h1pk u32 [2][B][H] 128KB
    char* wsb = (char*)d_ws;
    uint32* ctrl = (uint32*)wsb;
    uint32* h0pk = (uint32*)(wsb + 4096);
    uint32* h1pk = (uint32*)(wsb + 4096 + 262144);
    const size_t zero_bytes = 4096 + 262144 + 131072;   // 397312

    static const size_t lds_bytes = (size_t)(64 * KTOT) * sizeof(short)
                                  + (size_t)8 * 2 * 64 * 4 * sizeof(float); // 147456
    hipFuncSetAttribute((const void*)lstm_persist,
                        hipFuncAttributeMaxDynamicSharedMemorySize, (int)lds_bytes);

    hipMemsetAsync(d_ws, 0, zero_bytes, stream);
    hipLaunchKernelGGL(lstm_persist, dim3(128), dim3(512), lds_bytes, stream,
                       x, Wi, bi, Ws, bs, out, ctrl, h0pk, h1pk);
}

// Round 4
// 8260.505 us; speedup vs baseline: 1.0740x; 1.0740x over previous
//
#include <hip/hip_runtime.h>

// residual_LSTM: B=32, T=1024, H=C=512, L=2, fp32 in/out.
// R8: R6 barrier mechanics restored (post-R7 regression: scattered-slot gather poll
// serialized at one LLC slice; single-line flag poll is the right structure), plus:
//  (a) Layer-split hierarchical barrier: 16 groups x 8 WGs, RMW arrival, flags 0-7 = L0
//      groups, 8-15 = L1 groups, ALL in one 64B line -> poll is one load. Skewed
//      conditions: L0 waits L0flags>=e && L1flags>=e-2 (h0pk 4-deep, lead<=2);
//      L1 waits all>=e. Decouples the two 64-WG pools' jitter.
//  (b) x register prefetch (from R7): x(t+1) into 16xfloat4 VGPRs during the barrier
//      window -> L0's x-MFMA starts with zero load wait.
//  (c) Deferred out-store: out[] is never read device-side; store moved AFTER the
//      pre-arrival __syncthreads so its HBM completion overlaps the poll window
//      instead of sitting in the vmcnt(0) drain on L1's pacing chain.
// Carried: 128 WGs x 8ch, 2 N-tiles/wave, packed hi|lo bf16 h exchange over LLC
// (sc0 sc1, no fences), resid prefetch, fast exp/rcp transcendentals.

typedef unsigned int uint32;
typedef unsigned short ushort;

constexpr int B = 32, T = 1024, H = 512, NL = 2;
constexpr int KTOT = 2 * H;            // 1024 (combined [x;h] k-dim)
constexpr int BH   = B * H;            // 16384
constexpr size_t BTH = (size_t)B * T * H;
constexpr size_t BLH = (size_t)B * NL * H;

using bf16x8  = __attribute__((ext_vector_type(8))) short;
using floatx4 = __attribute__((ext_vector_type(4))) float;
using uint4v  = __attribute__((ext_vector_type(4))) uint32;

__device__ __forceinline__ float frcp(float x) { return __builtin_amdgcn_rcpf(x); }
__device__ __forceinline__ float sigm(float v) { return frcp(1.0f + __expf(-v)); }
__device__ __forceinline__ float tanh_fast(float v) {
    return 1.0f - 2.0f * frcp(1.0f + __expf(2.0f * v));
}

__device__ __forceinline__ ushort f2bf(float f) {        // RNE fp32 -> bf16 bits
    uint32 u = __builtin_bit_cast(uint32, f);
    u += 0x7fffu + ((u >> 16) & 1u);
    return (ushort)(u >> 16);
}

__launch_bounds__(512, 1)
__global__ void lstm_persist(const float* __restrict__ x,
                             const float* __restrict__ Wi,
                             const float* __restrict__ bi,
                             const float* __restrict__ Ws,
                             const float* __restrict__ bs,
                             float* __restrict__ out,
                             uint32* __restrict__ ctrl,
                             uint32* __restrict__ h0pk,   // [4][B][H] packed hi|lo<<16
                             uint32* __restrict__ h1pk)   // [2][B][H]
{
    extern __shared__ short smem[];
    short* whi = smem;                       // [32 rows][1024 k] bf16, swizzled 16B chunks
    short* wlo = smem + 32 * KTOT;
    float* red = (float*)(smem + 64 * KTOT); // [8 waves][2 nt][64 lanes][4] fp32 (16KB)

    const int wg    = blockIdx.x;            // 0..127
    const int tid   = threadIdx.x;           // 0..511
    const int layer = wg & 1;
    const int rg    = wg >> 1;               // row-group 0..63
    const int chb   = rg * 8;                // 8 channels per WG

    // ---- stage + hi/lo split weights into LDS (once). local row n = gate*8 + c ----
    for (int i = tid; i < 32 * KTOT; i += 512) {
        const int n = i >> 10, k = i & (KTOT - 1);
        const int g = n >> 3, c = n & 7;
        const int grow = g * H + chb + c;
        const float v = (k < H) ? Wi[((size_t)layer * 4 * H + grow) * H + k]
                                : Ws[((size_t)layer * 4 * H + grow) * H + (k - H)];
        const ushort hb = f2bf(v);
        const float  hf = __builtin_bit_cast(float, (uint32)hb << 16);
        const ushort lb = f2bf(v - hf);
        const int off = (n * 128 + ((k >> 3) ^ n)) * 8 + (k & 7);   // XOR chunk swizzle
        whi[off] = (short)hb;
        wlo[off] = (short)lb;
    }

    const int lane = tid & 63;
    const int w    = tid >> 6;               // wave 0..7
    const int mt   = w & 1;                  // M-tile (batches mt*16..mt*16+15)
    const int kq   = w >> 1;                 // k-quarter (256 k each)
    const int quad = lane >> 4;
    const int mrow = lane & 15;
    const int bb   = mt * 16 + mrow;         // this lane's batch in A-frag
    const int nn   = mrow;                   // this lane's row within a B-tile

    const int ec = tid & 7, eb = tid >> 3;   // epilogue mapping (tid < 256)
    float cs = 0.f;
    float bias_[4] = {0.f, 0.f, 0.f, 0.f};
    if (tid < 256) {
        #pragma unroll
        for (int g = 0; g < 4; ++g) {
            const int grow = g * H + chb + ec;
            bias_[g] = bi[layer * 4 * H + grow] + bs[layer * 4 * H + grow];
        }
    }

    // ---- x prefetch registers (L0 x-path waves only): x(t) resident in VGPRs ----
    const bool xwave = (layer == 0) && (kq < 2);
    float4 xq[16];
    if (xwave) {
        const float* xb = x + ((size_t)bb * T + 0) * H + kq * 256 + quad * 8;
        #pragma unroll
        for (int st = 0; st < 8; ++st) {
            xq[2 * st]     = *(const float4*)(xb + st * 32);
            xq[2 * st + 1] = *(const float4*)(xb + st * 32 + 4);
        }
    }
    __syncthreads();

    for (int s = 0; s <= T; ++s) {
        const int t = (layer == 0) ? s : s - 1;
        const bool active = (t >= 0 && t < T);

        // ---- residual prefetch: issued before MFMA work, consumed in epilogue ----
        float resid = 0.f;
        if (active && tid < 256) {
            const int ch = chb + ec;
            if (layer == 0) {
                resid = x[((size_t)eb * T + t) * H + ch];
            } else {
                const uint32 rp = __hip_atomic_load(
                    &h0pk[(size_t)(t & 3) * BH + (size_t)eb * H + ch],
                    __ATOMIC_RELAXED, __HIP_MEMORY_SCOPE_AGENT);
                resid = __builtin_bit_cast(float, rp << 16)
                      + __builtin_bit_cast(float, rp & 0xffff0000u);
            }
        }

        if (active) {
            floatx4 acc0 = {0.f, 0.f, 0.f, 0.f};   // nt0 hi
            floatx4 acc1 = {0.f, 0.f, 0.f, 0.f};   // nt0 lo-corrections
            floatx4 acc2 = {0.f, 0.f, 0.f, 0.f};   // nt1 hi
            floatx4 acc3 = {0.f, 0.f, 0.f, 0.f};   // nt1 lo-corrections

            if (xwave) {
                // x path: data already in VGPRs (prefetched last step), split on the fly
                #pragma unroll
                for (int st = 0; st < 8; ++st) {
                    const float4 f0 = xq[2 * st], f1 = xq[2 * st + 1];
                    const float vv[8] = {f0.x, f0.y, f0.z, f0.w, f1.x, f1.y, f1.z, f1.w};
                    bf16x8 ahi, alo;
                    #pragma unroll
                    for (int j = 0; j < 8; ++j) {
                        const ushort hb = f2bf(vv[j]);
                        const float  hf = __builtin_bit_cast(float, (uint32)hb << 16);
                        ahi[j] = (short)hb;
                        alo[j] = (short)f2bf(vv[j] - hf);
                    }
                    const int cb = kq * 32 + st * 4 + quad;
                    const int n1 = 16 + nn;
                    const int woff0 = (nn * 128 + (cb ^ nn)) * 8;
                    const int woff1 = (n1 * 128 + (cb ^ n1)) * 8;
                    const bf16x8 bh0 = *(const bf16x8*)(whi + woff0);
                    const bf16x8 bl0 = *(const bf16x8*)(wlo + woff0);
                    const bf16x8 bh1 = *(const bf16x8*)(whi + woff1);
                    const bf16x8 bl1 = *(const bf16x8*)(wlo + woff1);
                    acc0 = __builtin_amdgcn_mfma_f32_16x16x32_bf16(ahi, bh0, acc0, 0, 0, 0);
                    acc1 = __builtin_amdgcn_mfma_f32_16x16x32_bf16(alo, bh0, acc1, 0, 0, 0);
                    acc1 = __builtin_amdgcn_mfma_f32_16x16x32_bf16(ahi, bl0, acc1, 0, 0, 0);
                    acc2 = __builtin_amdgcn_mfma_f32_16x16x32_bf16(ahi, bh1, acc2, 0, 0, 0);
                    acc3 = __builtin_amdgcn_mfma_f32_16x16x32_bf16(alo, bh1, acc3, 0, 0, 0);
                    acc3 = __builtin_amdgcn_mfma_f32_16x16x32_bf16(ahi, bl1, acc3, 0, 0, 0);
                }
            } else {
                // h path: packed coherent loads direct from LLC (sc0 sc1), one vmcnt wait
                int par, koff;
                const uint32* hbuf;
                if (layer == 0)   { par = (t - 1) & 3; koff = kq * 256 - 512; hbuf = h0pk; }
                else if (kq < 2)  { par = t & 3;       koff = kq * 256;       hbuf = h0pk; }
                else              { par = (t - 1) & 1; koff = kq * 256 - 512; hbuf = h1pk; }
                const uint32* hp = hbuf + (size_t)par * BH + (size_t)bb * H + koff + quad * 8;

                uint4v q0,q1,q2,q3,q4,q5,q6,q7,q8,q9,q10,q11,q12,q13,q14,q15;
                asm volatile(
                    "global_load_dwordx4 %0,  %16, off sc0 sc1\n\t"
                    "global_load_dwordx4 %1,  %16, off offset:16 sc0 sc1\n\t"
                    "global_load_dwordx4 %2,  %16, off offset:128 sc0 sc1\n\t"
                    "global_load_dwordx4 %3,  %16, off offset:144 sc0 sc1\n\t"
                    "global_load_dwordx4 %4,  %16, off offset:256 sc0 sc1\n\t"
                    "global_load_dwordx4 %5,  %16, off offset:272 sc0 sc1\n\t"
                    "global_load_dwordx4 %6,  %16, off offset:384 sc0 sc1\n\t"
                    "global_load_dwordx4 %7,  %16, off offset:400 sc0 sc1\n\t"
                    "global_load_dwordx4 %8,  %16, off offset:512 sc0 sc1\n\t"
                    "global_load_dwordx4 %9,  %16, off offset:528 sc0 sc1\n\t"
                    "global_load_dwordx4 %10, %16, off offset:640 sc0 sc1\n\t"
                    "global_load_dwordx4 %11, %16, off offset:656 sc0 sc1\n\t"
                    "global_load_dwordx4 %12, %16, off offset:768 sc0 sc1\n\t"
                    "global_load_dwordx4 %13, %16, off offset:784 sc0 sc1\n\t"
                    "global_load_dwordx4 %14, %16, off offset:896 sc0 sc1\n\t"
                    "global_load_dwordx4 %15, %16, off offset:912 sc0 sc1\n\t"
                    "s_waitcnt vmcnt(0)"
                    : "=&v"(q0), "=&v"(q1), "=&v"(q2), "=&v"(q3),
                      "=&v"(q4), "=&v"(q5), "=&v"(q6), "=&v"(q7),
                      "=&v"(q8), "=&v"(q9), "=&v"(q10), "=&v"(q11),
                      "=&v"(q12), "=&v"(q13), "=&v"(q14), "=&v"(q15)
                    : "v"(hp)
                    : "memory");
                const uint4v qq[16] = {q0,q1,q2,q3,q4,q5,q6,q7,q8,q9,q10,q11,q12,q13,q14,q15};

                #pragma unroll
                for (int st = 0; st < 8; ++st) {
                    const uint4v ea = qq[2 * st], eb4 = qq[2 * st + 1];   // elems 0-3, 4-7
                    uint4v hiw, low;
                    hiw[0] = __builtin_amdgcn_perm(ea[1],  ea[0],  0x05040100u);
                    hiw[1] = __builtin_amdgcn_perm(ea[3],  ea[2],  0x05040100u);
                    hiw[2] = __builtin_amdgcn_perm(eb4[1], eb4[0], 0x05040100u);
                    hiw[3] = __builtin_amdgcn_perm(eb4[3], eb4[2], 0x05040100u);
                    low[0] = __builtin_amdgcn_perm(ea[1],  ea[0],  0x07060302u);
                    low[1] = __builtin_amdgcn_perm(ea[3],  ea[2],  0x07060302u);
                    low[2] = __builtin_amdgcn_perm(eb4[1], eb4[0], 0x07060302u);
                    low[3] = __builtin_amdgcn_perm(eb4[3], eb4[2], 0x07060302u);
                    const bf16x8 ahi = __builtin_bit_cast(bf16x8, hiw);
                    const bf16x8 alo = __builtin_bit_cast(bf16x8, low);
                    const int cb = kq * 32 + st * 4 + quad;
                    const int n1 = 16 + nn;
                    const int woff0 = (nn * 128 + (cb ^ nn)) * 8;
                    const int woff1 = (n1 * 128 + (cb ^ n1)) * 8;
                    const bf16x8 bh0 = *(const bf16x8*)(whi + woff0);
                    const bf16x8 bl0 = *(const bf16x8*)(wlo + woff0);
                    const bf16x8 bh1 = *(const bf16x8*)(whi + woff1);
                    const bf16x8 bl1 = *(const bf16x8*)(wlo + woff1);
                    acc0 = __builtin_amdgcn_mfma_f32_16x16x32_bf16(ahi, bh0, acc0, 0, 0, 0);
                    acc1 = __builtin_amdgcn_mfma_f32_16x16x32_bf16(alo, bh0, acc1, 0, 0, 0);
                    acc1 = __builtin_amdgcn_mfma_f32_16x16x32_bf16(ahi, bl0, acc1, 0, 0, 0);
                    acc2 = __builtin_amdgcn_mfma_f32_16x16x32_bf16(ahi, bh1, acc2, 0, 0, 0);
                    acc3 = __builtin_amdgcn_mfma_f32_16x16x32_bf16(alo, bh1, acc3, 0, 0, 0);
                    acc3 = __builtin_amdgcn_mfma_f32_16x16x32_bf16(ahi, bl1, acc3, 0, 0, 0);
                }
            }
            floatx4 zr0, zr1;
            zr0[0] = acc0[0] + acc1[0]; zr0[1] = acc0[1] + acc1[1];
            zr0[2] = acc0[2] + acc1[2]; zr0[3] = acc0[3] + acc1[3];
            zr1[0] = acc2[0] + acc3[0]; zr1[1] = acc2[1] + acc3[1];
            zr1[2] = acc2[2] + acc3[2]; zr1[3] = acc2[3] + acc3[3];
            *(floatx4*)&red[((w * 2 + 0) * 64 + lane) * 4] = zr0;
            *(floatx4*)&red[((w * 2 + 1) * 64 + lane) * 4] = zr1;
        }
        __syncthreads();   // red visible to epilogue

        float hn_s = 0.f;
        if (active && tid < 256) {
            // D layout (m89): col = lane&15, row(m) = (lane>>4)*4 + reg
            const int m = eb & 15, emt = eb >> 4, q = m >> 2, r = m & 3;
            const int ch = chb + ec;
            float z[4];
            #pragma unroll
            for (int g = 0; g < 4; ++g) {
                const int n = g * 8 + ec;          // local row 0..31
                const int nt = n >> 4, col = n & 15;
                const int li = q * 16 + col;
                float a = bias_[g];
                #pragma unroll
                for (int kqe = 0; kqe < 4; ++kqe)
                    a += red[((((kqe * 2 + emt) * 2) + nt) * 64 + li) * 4 + r];
                z[g] = a;
            }
            const float ig = sigm(z[0]), fg = sigm(z[1]);
            const float gg = tanh_fast(z[2]), og = sigm(z[3]);
            cs = ig * gg + fg * cs;
            hn_s = og * tanh_fast(cs) + resid;

            const ushort hb = f2bf(hn_s);
            const float  hf = __builtin_bit_cast(float, (uint32)hb << 16);
            const ushort lb = f2bf(hn_s - hf);
            const uint32 pk = (uint32)hb | ((uint32)lb << 16);
            if (layer == 0) {
                const size_t hidx = (size_t)(t & 3) * BH + (size_t)eb * H + ch;
                __hip_atomic_store(&h0pk[hidx], pk, __ATOMIC_RELAXED, __HIP_MEMORY_SCOPE_AGENT);
            } else {
                const size_t hidx = (size_t)(t & 1) * BH + (size_t)eb * H + ch;
                __hip_atomic_store(&h1pk[hidx], pk, __ATOMIC_RELAXED, __HIP_MEMORY_SCOPE_AGENT);
            }
        }

        // Drain point: h stores must be LLC-visible before arrival. out[] is NOT read
        // device-side -> its store is issued AFTER this sync, completing during the
        // poll window instead of inside the drain.
        __syncthreads();

        if (active && tid < 256) {
            const int ch = chb + ec;
            if (layer == 1)
                out[((size_t)eb * T + t) * H + ch] = hn_s;
            if (t == T - 1) {
                out[BTH + ((size_t)eb * NL + layer) * H + ch] = hn_s;
                out[BTH + BLH + ((size_t)eb * NL + layer) * H + ch] = cs;
            }
        }

        if (s < T) {
            // x prefetch for next step: vmcnt drain lands inside the poll window.
            if (xwave && (s + 1) < T) {
                const float* xb = x + ((size_t)bb * T + (s + 1)) * H + kq * 256 + quad * 8;
                #pragma unroll
                for (int st = 0; st < 8; ++st) {
                    xq[2 * st]     = *(const float4*)(xb + st * 32);
                    xq[2 * st + 1] = *(const float4*)(xb + st * 32 + 4);
                }
            }
            const uint32 e = (uint32)s + 1u;
            // Arrival: hierarchical RMW. Groups: layer*8 + (rg>>3), counters 128B apart.
            if (tid == 0) {
                const int grp = layer * 8 + (rg >> 3);
                uint32* gcnt = ctrl + grp * 32;
                const uint32 rr = __hip_atomic_fetch_add(gcnt, 1u, __ATOMIC_RELAXED,
                                                         __HIP_MEMORY_SCOPE_AGENT);
                if (rr == e * 8u - 1u)
                    __hip_atomic_store(&ctrl[512 + grp], e,
                                       __ATOMIC_RELAXED, __HIP_MEMORY_SCOPE_AGENT);
            }
            // Release: ONE 64B flag line. flags 0-7 = L0 groups, 8-15 = L1 groups.
            // L0 waits L0flags>=e && L1flags>=e-2 (4-deep h0pk, lead<=2); L1 all>=e.
            if (tid < 64) {
                const int fidx = tid & 15;
                const uint32 thr = (layer == 0 && fidx >= 8)
                                 ? (e >= 2u ? e - 2u : 0u) : e;
                const uint32* fp = ctrl + 512 + fidx;
                for (;;) {
                    uint32 f;
                    asm volatile("global_load_dword %0, %1, off sc0 sc1\n\t"
                                 "s_waitcnt vmcnt(0)"
                                 : "=v"(f) : "v"(fp) : "memory");
                    if (__all(f >= thr)) break;
                    __builtin_amdgcn_s_sleep(1);
                }
            }
            __syncthreads();
        }
    }
}

extern "C" void kernel_launch(void* const* d_in, const int* in_sizes, int n_in,
                              void* d_out, int out_size, void* d_ws, size_t ws_size,
                              hipStream_t stream) {
    const float* x  = (const float*)d_in[0];
    const float* Wi = (const float*)d_in[1];
    const float* bi = (const float*)d_in[2];
    const float* Ws = (const float*)d_in[3];
    const float* bs = (const float*)d_in[4];
    float* out = (float*)d_out;

    // ws: ctrl 4KB (counters g*128B, flags @ +2048) | h0pk [4][B][H] 256KB | h1pk 128KB
    char* wsb = (char*)d_ws;
    uint32* ctrl = (uint32*)wsb;
    uint32* h0pk = (uint32*)(wsb + 4096);
    uint32* h1pk = (uint32*)(wsb + 4096 + 262144);
    const size_t zero_bytes = 4096 + 262144 + 131072;   // 397312

    static const size_t lds_bytes = (size_t)(64 * KTOT) * sizeof(short)
                                  + (size_t)8 * 2 * 64 * 4 * sizeof(float); // 147456
    hipFuncSetAttribute((const void*)lstm_persist,
                        hipFuncAttributeMaxDynamicSharedMemorySize, (int)lds_bytes);

    hipMemsetAsync(d_ws, 0, zero_bytes, stream);
    hipLaunchKernelGGL(lstm_persist, dim3(128), dim3(512), lds_bytes, stream,
                       x, Wi, bi, Ws, bs, out, ctrl, h0pk, h1pk);
}

// Round 5
// 6673.199 us; speedup vs baseline: 1.3295x; 1.2379x over previous
//
#include <hip/hip_runtime.h>

// residual_LSTM: B=32, T=1024, H=C=512, L=2, fp32 in/out.
// R9: exact R6 structure (best verified: 7907us) + correctly-ORDERED overlap work.
// R7/R8 post-mortem: prefetch loads issued BEFORE the arrival RMW in the same wave
// stretched the last-arriver path by a load latency every step. Fix by wave role split:
//  - Wave 7 (tid 448-511, no epilogue duties, clean vmcnt after drain): does the
//    arrival RMW FIRST (nothing precedes it), then polls the single 64B flag line.
//  - Waves 0-3: deferred out[] stores + x(t+1) VGPR prefetch issued after the drain
//    sync, overlapping wave 7's arrival+poll; they park at the closing syncthreads.
// Barrier mechanics = R6 verbatim: 16 groups x 8 WGs, hierarchical RMW arrival,
// 16 flags in ONE 64B line, uniform all>=e condition, 2-deep h0pk/h1pk.
// Carried: 128 WGs x 8ch, 2 N-tiles/wave, packed hi|lo bf16 h exchange (sc0 sc1),
// resid prefetch at top of step, fast exp/rcp transcendentals.

typedef unsigned int uint32;
typedef unsigned short ushort;

constexpr int B = 32, T = 1024, H = 512, NL = 2;
constexpr int KTOT = 2 * H;            // 1024 (combined [x;h] k-dim)
constexpr int BH   = B * H;            // 16384
constexpr size_t BTH = (size_t)B * T * H;
constexpr size_t BLH = (size_t)B * NL * H;

using bf16x8  = __attribute__((ext_vector_type(8))) short;
using floatx4 = __attribute__((ext_vector_type(4))) float;
using uint4v  = __attribute__((ext_vector_type(4))) uint32;

__device__ __forceinline__ float frcp(float x) { return __builtin_amdgcn_rcpf(x); }
__device__ __forceinline__ float sigm(float v) { return frcp(1.0f + __expf(-v)); }
__device__ __forceinline__ float tanh_fast(float v) {
    return 1.0f - 2.0f * frcp(1.0f + __expf(2.0f * v));
}

__device__ __forceinline__ ushort f2bf(float f) {        // RNE fp32 -> bf16 bits
    uint32 u = __builtin_bit_cast(uint32, f);
    u += 0x7fffu + ((u >> 16) & 1u);
    return (ushort)(u >> 16);
}

__launch_bounds__(512, 1)
__global__ void lstm_persist(const float* __restrict__ x,
                             const float* __restrict__ Wi,
                             const float* __restrict__ bi,
                             const float* __restrict__ Ws,
                             const float* __restrict__ bs,
                             float* __restrict__ out,
                             uint32* __restrict__ ctrl,
                             uint32* __restrict__ h0pk,   // [2][B][H] packed hi|lo<<16
                             uint32* __restrict__ h1pk)   // [2][B][H]
{
    extern __shared__ short smem[];
    short* whi = smem;                       // [32 rows][1024 k] bf16, swizzled 16B chunks
    short* wlo = smem + 32 * KTOT;
    float* red = (float*)(smem + 64 * KTOT); // [8 waves][2 nt][64 lanes][4] fp32 (16KB)

    const int wg    = blockIdx.x;            // 0..127
    const int tid   = threadIdx.x;           // 0..511
    const int layer = wg & 1;
    const int rg    = wg >> 1;               // row-group 0..63
    const int chb   = rg * 8;                // 8 channels per WG

    // ---- stage + hi/lo split weights into LDS (once). local row n = gate*8 + c ----
    for (int i = tid; i < 32 * KTOT; i += 512) {
        const int n = i >> 10, k = i & (KTOT - 1);
        const int g = n >> 3, c = n & 7;
        const int grow = g * H + chb + c;
        const float v = (k < H) ? Wi[((size_t)layer * 4 * H + grow) * H + k]
                                : Ws[((size_t)layer * 4 * H + grow) * H + (k - H)];
        const ushort hb = f2bf(v);
        const float  hf = __builtin_bit_cast(float, (uint32)hb << 16);
        const ushort lb = f2bf(v - hf);
        const int off = (n * 128 + ((k >> 3) ^ n)) * 8 + (k & 7);   // XOR chunk swizzle
        whi[off] = (short)hb;
        wlo[off] = (short)lb;
    }

    const int lane = tid & 63;
    const int w    = tid >> 6;               // wave 0..7
    const int mt   = w & 1;                  // M-tile (batches mt*16..mt*16+15)
    const int kq   = w >> 1;                 // k-quarter (256 k each)
    const int quad = lane >> 4;
    const int mrow = lane & 15;
    const int bb   = mt * 16 + mrow;         // this lane's batch in A-frag
    const int nn   = mrow;                   // this lane's row within a B-tile

    const int ec = tid & 7, eb = tid >> 3;   // epilogue mapping (tid < 256)
    float cs = 0.f;
    float bias_[4] = {0.f, 0.f, 0.f, 0.f};
    if (tid < 256) {
        #pragma unroll
        for (int g = 0; g < 4; ++g) {
            const int grow = g * H + chb + ec;
            bias_[g] = bi[layer * 4 * H + grow] + bs[layer * 4 * H + grow];
        }
    }

    // ---- x prefetch registers (L0 x-path waves = waves 0-3): x(t) resident in VGPRs ----
    const bool xwave = (layer == 0) && (kq < 2);
    float4 xq[16];
    if (xwave) {
        const float* xb = x + ((size_t)bb * T + 0) * H + kq * 256 + quad * 8;
        #pragma unroll
        for (int st = 0; st < 8; ++st) {
            xq[2 * st]     = *(const float4*)(xb + st * 32);
            xq[2 * st + 1] = *(const float4*)(xb + st * 32 + 4);
        }
    }
    __syncthreads();

    for (int s = 0; s <= T; ++s) {
        const int t = (layer == 0) ? s : s - 1;
        const bool active = (t >= 0 && t < T);

        // ---- residual prefetch: issued before MFMA work, consumed in epilogue ----
        float resid = 0.f;
        if (active && tid < 256) {
            const int ch = chb + ec;
            if (layer == 0) {
                resid = x[((size_t)eb * T + t) * H + ch];
            } else {
                const uint32 rp = __hip_atomic_load(
                    &h0pk[(size_t)(t & 1) * BH + (size_t)eb * H + ch],
                    __ATOMIC_RELAXED, __HIP_MEMORY_SCOPE_AGENT);
                resid = __builtin_bit_cast(float, rp << 16)
                      + __builtin_bit_cast(float, rp & 0xffff0000u);
            }
        }

        if (active) {
            floatx4 acc0 = {0.f, 0.f, 0.f, 0.f};   // nt0 hi
            floatx4 acc1 = {0.f, 0.f, 0.f, 0.f};   // nt0 lo-corrections
            floatx4 acc2 = {0.f, 0.f, 0.f, 0.f};   // nt1 hi
            floatx4 acc3 = {0.f, 0.f, 0.f, 0.f};   // nt1 lo-corrections

            if (xwave) {
                // x path: data already in VGPRs (prefetched during last poll window)
                #pragma unroll
                for (int st = 0; st < 8; ++st) {
                    const float4 f0 = xq[2 * st], f1 = xq[2 * st + 1];
                    const float vv[8] = {f0.x, f0.y, f0.z, f0.w, f1.x, f1.y, f1.z, f1.w};
                    bf16x8 ahi, alo;
                    #pragma unroll
                    for (int j = 0; j < 8; ++j) {
                        const ushort hb = f2bf(vv[j]);
                        const float  hf = __builtin_bit_cast(float, (uint32)hb << 16);
                        ahi[j] = (short)hb;
                        alo[j] = (short)f2bf(vv[j] - hf);
                    }
                    const int cb = kq * 32 + st * 4 + quad;
                    const int n1 = 16 + nn;
                    const int woff0 = (nn * 128 + (cb ^ nn)) * 8;
                    const int woff1 = (n1 * 128 + (cb ^ n1)) * 8;
                    const bf16x8 bh0 = *(const bf16x8*)(whi + woff0);
                    const bf16x8 bl0 = *(const bf16x8*)(wlo + woff0);
                    const bf16x8 bh1 = *(const bf16x8*)(whi + woff1);
                    const bf16x8 bl1 = *(const bf16x8*)(wlo + woff1);
                    acc0 = __builtin_amdgcn_mfma_f32_16x16x32_bf16(ahi, bh0, acc0, 0, 0, 0);
                    acc1 = __builtin_amdgcn_mfma_f32_16x16x32_bf16(alo, bh0, acc1, 0, 0, 0);
                    acc1 = __builtin_amdgcn_mfma_f32_16x16x32_bf16(ahi, bl0, acc1, 0, 0, 0);
                    acc2 = __builtin_amdgcn_mfma_f32_16x16x32_bf16(ahi, bh1, acc2, 0, 0, 0);
                    acc3 = __builtin_amdgcn_mfma_f32_16x16x32_bf16(alo, bh1, acc3, 0, 0, 0);
                    acc3 = __builtin_amdgcn_mfma_f32_16x16x32_bf16(ahi, bl1, acc3, 0, 0, 0);
                }
            } else {
                // h path: packed coherent loads direct from LLC (sc0 sc1), one vmcnt wait
                int par, koff;
                const uint32* hbuf;
                if (layer == 0)   { par = (t - 1) & 1; koff = kq * 256 - 512; hbuf = h0pk; }
                else if (kq < 2)  { par = t & 1;       koff = kq * 256;       hbuf = h0pk; }
                else              { par = (t - 1) & 1; koff = kq * 256 - 512; hbuf = h1pk; }
                const uint32* hp = hbuf + (size_t)par * BH + (size_t)bb * H + koff + quad * 8;

                uint4v q0,q1,q2,q3,q4,q5,q6,q7,q8,q9,q10,q11,q12,q13,q14,q15;
                asm volatile(
                    "global_load_dwordx4 %0,  %16, off sc0 sc1\n\t"
                    "global_load_dwordx4 %1,  %16, off offset:16 sc0 sc1\n\t"
                    "global_load_dwordx4 %2,  %16, off offset:128 sc0 sc1\n\t"
                    "global_load_dwordx4 %3,  %16, off offset:144 sc0 sc1\n\t"
                    "global_load_dwordx4 %4,  %16, off offset:256 sc0 sc1\n\t"
                    "global_load_dwordx4 %5,  %16, off offset:272 sc0 sc1\n\t"
                    "global_load_dwordx4 %6,  %16, off offset:384 sc0 sc1\n\t"
                    "global_load_dwordx4 %7,  %16, off offset:400 sc0 sc1\n\t"
                    "global_load_dwordx4 %8,  %16, off offset:512 sc0 sc1\n\t"
                    "global_load_dwordx4 %9,  %16, off offset:528 sc0 sc1\n\t"
                    "global_load_dwordx4 %10, %16, off offset:640 sc0 sc1\n\t"
                    "global_load_dwordx4 %11, %16, off offset:656 sc0 sc1\n\t"
                    "global_load_dwordx4 %12, %16, off offset:768 sc0 sc1\n\t"
                    "global_load_dwordx4 %13, %16, off offset:784 sc0 sc1\n\t"
                    "global_load_dwordx4 %14, %16, off offset:896 sc0 sc1\n\t"
                    "global_load_dwordx4 %15, %16, off offset:912 sc0 sc1\n\t"
                    "s_waitcnt vmcnt(0)"
                    : "=&v"(q0), "=&v"(q1), "=&v"(q2), "=&v"(q3),
                      "=&v"(q4), "=&v"(q5), "=&v"(q6), "=&v"(q7),
                      "=&v"(q8), "=&v"(q9), "=&v"(q10), "=&v"(q11),
                      "=&v"(q12), "=&v"(q13), "=&v"(q14), "=&v"(q15)
                    : "v"(hp)
                    : "memory");
                const uint4v qq[16] = {q0,q1,q2,q3,q4,q5,q6,q7,q8,q9,q10,q11,q12,q13,q14,q15};

                #pragma unroll
                for (int st = 0; st < 8; ++st) {
                    const uint4v ea = qq[2 * st], eb4 = qq[2 * st + 1];   // elems 0-3, 4-7
                    uint4v hiw, low;
                    hiw[0] = __builtin_amdgcn_perm(ea[1],  ea[0],  0x05040100u);
                    hiw[1] = __builtin_amdgcn_perm(ea[3],  ea[2],  0x05040100u);
                    hiw[2] = __builtin_amdgcn_perm(eb4[1], eb4[0], 0x05040100u);
                    hiw[3] = __builtin_amdgcn_perm(eb4[3], eb4[2], 0x05040100u);
                    low[0] = __builtin_amdgcn_perm(ea[1],  ea[0],  0x07060302u);
                    low[1] = __builtin_amdgcn_perm(ea[3],  ea[2],  0x07060302u);
                    low[2] = __builtin_amdgcn_perm(eb4[1], eb4[0], 0x07060302u);
                    low[3] = __builtin_amdgcn_perm(eb4[3], eb4[2], 0x07060302u);
                    const bf16x8 ahi = __builtin_bit_cast(bf16x8, hiw);
                    const bf16x8 alo = __builtin_bit_cast(bf16x8, low);
                    const int cb = kq * 32 + st * 4 + quad;
                    const int n1 = 16 + nn;
                    const int woff0 = (nn * 128 + (cb ^ nn)) * 8;
                    const int woff1 = (n1 * 128 + (cb ^ n1)) * 8;
                    const bf16x8 bh0 = *(const bf16x8*)(whi + woff0);
                    const bf16x8 bl0 = *(const bf16x8*)(wlo + woff0);
                    const bf16x8 bh1 = *(const bf16x8*)(whi + woff1);
                    const bf16x8 bl1 = *(const bf16x8*)(wlo + woff1);
                    acc0 = __builtin_amdgcn_mfma_f32_16x16x32_bf16(ahi, bh0, acc0, 0, 0, 0);
                    acc1 = __builtin_amdgcn_mfma_f32_16x16x32_bf16(alo, bh0, acc1, 0, 0, 0);
                    acc1 = __builtin_amdgcn_mfma_f32_16x16x32_bf16(ahi, bl0, acc1, 0, 0, 0);
                    acc2 = __builtin_amdgcn_mfma_f32_16x16x32_bf16(ahi, bh1, acc2, 0, 0, 0);
                    acc3 = __builtin_amdgcn_mfma_f32_16x16x32_bf16(alo, bh1, acc3, 0, 0, 0);
                    acc3 = __builtin_amdgcn_mfma_f32_16x16x32_bf16(ahi, bl1, acc3, 0, 0, 0);
                }
            }
            floatx4 zr0, zr1;
            zr0[0] = acc0[0] + acc1[0]; zr0[1] = acc0[1] + acc1[1];
            zr0[2] = acc0[2] + acc1[2]; zr0[3] = acc0[3] + acc1[3];
            zr1[0] = acc2[0] + acc3[0]; zr1[1] = acc2[1] + acc3[1];
            zr1[2] = acc2[2] + acc3[2]; zr1[3] = acc2[3] + acc3[3];
            *(floatx4*)&red[((w * 2 + 0) * 64 + lane) * 4] = zr0;
            *(floatx4*)&red[((w * 2 + 1) * 64 + lane) * 4] = zr1;
        }
        __syncthreads();   // red visible to epilogue

        float hn_s = 0.f;
        if (active && tid < 256) {
            // D layout (m89): col = lane&15, row(m) = (lane>>4)*4 + reg
            const int m = eb & 15, emt = eb >> 4, q = m >> 2, r = m & 3;
            const int ch = chb + ec;
            float z[4];
            #pragma unroll
            for (int g = 0; g < 4; ++g) {
                const int n = g * 8 + ec;          // local row 0..31
                const int nt = n >> 4, col = n & 15;
                const int li = q * 16 + col;
                float a = bias_[g];
                #pragma unroll
                for (int kqe = 0; kqe < 4; ++kqe)
                    a += red[((((kqe * 2 + emt) * 2) + nt) * 64 + li) * 4 + r];
                z[g] = a;
            }
            const float ig = sigm(z[0]), fg = sigm(z[1]);
            const float gg = tanh_fast(z[2]), og = sigm(z[3]);
            cs = ig * gg + fg * cs;
            hn_s = og * tanh_fast(cs) + resid;

            const ushort hb = f2bf(hn_s);
            const float  hf = __builtin_bit_cast(float, (uint32)hb << 16);
            const ushort lb = f2bf(hn_s - hf);
            const uint32 pk = (uint32)hb | ((uint32)lb << 16);
            const size_t hidx = (size_t)(t & 1) * BH + (size_t)eb * H + ch;
            if (layer == 0) {
                __hip_atomic_store(&h0pk[hidx], pk, __ATOMIC_RELAXED, __HIP_MEMORY_SCOPE_AGENT);
            } else {
                __hip_atomic_store(&h1pk[hidx], pk, __ATOMIC_RELAXED, __HIP_MEMORY_SCOPE_AGENT);
            }
        }

        // Drain point: h stores LLC-visible before arrival. Everything below overlaps
        // the barrier: wave 7 arrives FIRST (nothing precedes its RMW), waves 0-3 issue
        // out stores + x prefetch into the poll window, then park at the closing sync.
        __syncthreads();

        // Wave 7: arrival RMW immediately (last-arriver path stays minimal).
        if (tid == 448 && s < T) {
            const uint32 e = (uint32)s + 1u;
            uint32* gcnt = ctrl + (wg >> 3) * 32;
            const uint32 rr = __hip_atomic_fetch_add(gcnt, 1u, __ATOMIC_RELAXED,
                                                     __HIP_MEMORY_SCOPE_AGENT);
            if (rr == e * 8u - 1u)
                __hip_atomic_store(&ctrl[512 + (wg >> 3)], e,
                                   __ATOMIC_RELAXED, __HIP_MEMORY_SCOPE_AGENT);
        }

        // Waves 0-3: deferred out stores (out[] never read device-side).
        if (active && tid < 256) {
            const int ch = chb + ec;
            if (layer == 1)
                out[((size_t)eb * T + t) * H + ch] = hn_s;
            if (t == T - 1) {
                out[BTH + ((size_t)eb * NL + layer) * H + ch] = hn_s;
                out[BTH + BLH + ((size_t)eb * NL + layer) * H + ch] = cs;
            }
        }

        if (s < T) {
            // Waves 0-1 group (xwave): prefetch x(s+1) into VGPRs during poll window.
            if (xwave && (s + 1) < T) {
                const float* xb = x + ((size_t)bb * T + (s + 1)) * H + kq * 256 + quad * 8;
                #pragma unroll
                for (int st = 0; st < 8; ++st) {
                    xq[2 * st]     = *(const float4*)(xb + st * 32);
                    xq[2 * st + 1] = *(const float4*)(xb + st * 32 + 4);
                }
            }
            // Wave 7 polls the single 64B flag line (its vmcnt is clean).
            if (tid >= 448) {
                const uint32 e = (uint32)s + 1u;
                const uint32* fp = ctrl + 512 + (tid & 15);
                for (;;) {
                    uint32 f;
                    asm volatile("global_load_dword %0, %1, off sc0 sc1\n\t"
                                 "s_waitcnt vmcnt(0)"
                                 : "=v"(f) : "v"(fp) : "memory");
                    if (__all(f >= e)) break;
                    __builtin_amdgcn_s_sleep(1);
                }
            }
            __syncthreads();
        }
    }
}

extern "C" void kernel_launch(void* const* d_in, const int* in_sizes, int n_in,
                              void* d_out, int out_size, void* d_ws, size_t ws_size,
                              hipStream_t stream) {
    const float* x  = (const float*)d_in[0];
    const float* Wi = (const float*)d_in[1];
    const float* bi = (const float*)d_in[2];
    const float* Ws = (const float*)d_in[3];
    const float* bs = (const float*)d_in[4];
    float* out = (float*)d_out;

    // ws: ctrl 4KB (group counters g*128B, flags @ +2048) | h0pk [2][B][H] 128KB | h1pk 128KB
    char* wsb = (char*)d_ws;
    uint32* ctrl = (uint32*)wsb;
    uint32* h0pk = (uint32*)(wsb + 4096);
    uint32* h1pk = (uint32*)(wsb + 4096 + 131072);
    const size_t zero_bytes = 4096 + 2 * 131072;   // 266240

    static const size_t lds_bytes = (size_t)(64 * KTOT) * sizeof(short)
                                  + (size_t)8 * 2 * 64 * 4 * sizeof(float); // 147456
    hipFuncSetAttribute((const void*)lstm_persist,
                        hipFuncAttributeMaxDynamicSharedMemorySize, (int)lds_bytes);

    hipMemsetAsync(d_ws, 0, zero_bytes, stream);
    hipLaunchKernelGGL(lstm_persist, dim3(128), dim3(512), lds_bytes, stream,
                       x, Wi, bi, Ws, bs, out, ctrl, h0pk, h1pk);
}